// Round 3
// baseline (516.925 us; speedup 1.0000x reference)
//
#include <hip/hip_runtime.h>

// CorrelationLayer1D via bf16 MFMA band-matmul, v3.
// out[b,d,h,w] = sum_c x1[b,c,h,w] * x2[b,c,h,w+d-80]
// B=8 C=128 H=160 W=320 D=81.
//
// Block = (b, h, w-quarter of 80). 320 threads = 5 waves; wave s owns w-subtile
// [w0+16s, w0+16s+16). 6 N-tiles of 16 x2-cols cover the 96-col band.
// K staged in 4 chunks of 32 channels, transposed to bf16 LDS [w][c] (row
// stride 40 shorts = 80 B, 16B-aligned fragments).
// Epilogue: acc -> LDS [d][w] (stride 81) -> coalesced float4 stores.
// LDS = max(staging 19.2KB, epilogue 26.2KB) = 26368 B -> 6 blocks/CU.

#define CB 8
#define CC 128
#define CH 160
#define CW 320
#define CD 81
#define CPAD 80
#define TW 80
#define NTHR 320
#define AROWS 80
#define BROWS 160
#define KC 32
#define ROWP 40            // staging LDS row stride in shorts (80 B)
#define OSTRIDE 81         // epilogue LDS row stride in floats
#define HW (CH*CW)         // 51200
#define SMEM_BYTES 26368   // >= max(240*40*2=19200, 81*81*4=26244)

typedef __attribute__((ext_vector_type(8))) short short8;
typedef __attribute__((ext_vector_type(4))) float f32x4;

__device__ __forceinline__ unsigned pk2(float a, float b) {
    // round-to-nearest-even fp32 -> bf16, packed pair
    unsigned ua = __float_as_uint(a), ub = __float_as_uint(b);
    ua = (ua + 0x7fffu + ((ua >> 16) & 1u)) >> 16;
    ub = (ub + 0x7fffu + ((ub >> 16) & 1u)) >> 16;
    return ua | (ub << 16);
}

__global__ __launch_bounds__(NTHR, 8) void corr1d_mfma3(
    const float* __restrict__ x1,
    const float* __restrict__ x2,
    float* __restrict__ out)
{
    __shared__ __align__(16) char smem[SMEM_BYTES];
    unsigned short* lds = (unsigned short*)smem;   // staging [row][ROWP]
    float* obuf = (float*)smem;                    // epilogue [d][OSTRIDE]

    const int tid = threadIdx.x;
    const int bid = blockIdx.x;
    const int wt = bid & 3;
    const int h  = (bid >> 2) % CH;
    const int b  = bid / (4 * CH);
    const int w0 = wt * TW;

    const int lane = tid & 63;
    const int s    = tid >> 6;   // subtile 0..4
    const int n    = lane & 15;
    const int q    = lane >> 4;

    const float* x1p = x1 + ((size_t)b * CC * CH + (size_t)h) * CW;
    const float* x2p = x2 + ((size_t)b * CC * CH + (size_t)h) * CW;

    f32x4 acc[6];
#pragma unroll
    for (int t = 0; t < 6; t++) acc[t] = (f32x4){0.f, 0.f, 0.f, 0.f};

    for (int c0 = 0; c0 < CC; c0 += KC) {
        if (c0) __syncthreads();

        // ---- stage: 60 w-quads x 8 c-quads = 480 tiles of 4w x 4c ----
#pragma unroll
        for (int ii = 0; ii < 2; ii++) {
            int i = tid + ii * NTHR;
            if (i < 480) {
                int cq = i & 7;
                int rt = i >> 3;        // 0..19 -> A, 20..59 -> B
                int kl = cq << 2;       // k_local 0..28
                int c  = c0 + kl;
                float4 v[4];
                unsigned short* dst;
                if (rt < 20) {
                    const float* p = x1p + (size_t)c * HW + w0 + (rt << 2);
#pragma unroll
                    for (int cc = 0; cc < 4; cc++)
                        v[cc] = *(const float4*)(p + (size_t)cc * HW);
                    dst = lds + (rt << 2) * ROWP + kl;
                } else {
                    int rb = rt - 20;
                    int gw = w0 - CPAD + (rb << 2);
                    if (gw >= 0) {
                        const float* p = x2p + (size_t)c * HW + gw;
#pragma unroll
                        for (int cc = 0; cc < 4; cc++)
                            v[cc] = *(const float4*)(p + (size_t)cc * HW);
                    } else {
#pragma unroll
                        for (int cc = 0; cc < 4; cc++)
                            v[cc] = make_float4(0.f, 0.f, 0.f, 0.f);
                    }
                    dst = lds + (AROWS + (rb << 2)) * ROWP + kl;
                }
                // 4x4 register transpose, bf16-pack, 4 x ds_write_b64
                uint2 r0 = make_uint2(pk2(v[0].x, v[1].x), pk2(v[2].x, v[3].x));
                uint2 r1 = make_uint2(pk2(v[0].y, v[1].y), pk2(v[2].y, v[3].y));
                uint2 r2 = make_uint2(pk2(v[0].z, v[1].z), pk2(v[2].z, v[3].z));
                uint2 r3 = make_uint2(pk2(v[0].w, v[1].w), pk2(v[2].w, v[3].w));
                *(uint2*)(dst + 0 * ROWP) = r0;
                *(uint2*)(dst + 1 * ROWP) = r1;
                *(uint2*)(dst + 2 * ROWP) = r2;
                *(uint2*)(dst + 3 * ROWP) = r3;
            }
        }
        __syncthreads();

        // ---- compute: 1 K-step of 32, 6 N-tiles ----
        short8 av = *(const short8*)(lds + (16 * s + n) * ROWP + 8 * q);
#pragma unroll
        for (int t = 0; t < 6; t++) {
            short8 bv = *(const short8*)(lds + (AROWS + 16 * (s + t) + n) * ROWP + 8 * q);
            acc[t] = __builtin_amdgcn_mfma_f32_16x16x32_bf16(av, bv, acc[t], 0, 0, 0);
        }
    }
    __syncthreads();   // staging buffer -> epilogue buffer reuse

    // ---- epilogue: acc -> LDS [d][w_local], d = 16t + n - m, m = 4q+r ----
#pragma unroll
    for (int t = 0; t < 6; t++) {
#pragma unroll
        for (int r = 0; r < 4; r++) {
            int m = 4 * q + r;
            int d = 16 * t + n - m;
            if (d >= 0 && d <= CPAD)
                obuf[d * OSTRIDE + 16 * s + m] = acc[t][r];
        }
    }
    __syncthreads();

    // ---- coalesced store: 81 d-rows x 20 float4 = 1620 float4 ----
    float* op = out + ((size_t)b * CD * CH + (size_t)h) * CW + w0;
    for (int i = tid; i < CD * (TW / 4); i += NTHR) {
        int d  = i / (TW / 4);
        int wq = i - d * (TW / 4);
        const float* r0 = obuf + d * OSTRIDE + 4 * wq;
        float4 v = make_float4(r0[0], r0[1], r0[2], r0[3]);
        *(float4*)(op + (size_t)d * HW + 4 * wq) = v;
    }
}

extern "C" void kernel_launch(void* const* d_in, const int* in_sizes, int n_in,
                              void* d_out, int out_size, void* d_ws, size_t ws_size,
                              hipStream_t stream) {
    const float* x1 = (const float*)d_in[0];
    const float* x2 = (const float*)d_in[1];
    float* out = (float*)d_out;
    dim3 grid(CB * CH * 4);   // 5120
    dim3 block(NTHR);
    corr1d_mfma3<<<grid, block, 0, stream>>>(x1, x2, out);
}